// Round 12
// baseline (188.539 us; speedup 1.0000x reference)
//
#include <hip/hip_runtime.h>

#define NB 8192
#define NH 50
#define ND 64
#define MAXIT 13   // ceil(NH/4)

__device__ __forceinline__ float wsum(float v) {
#pragma unroll
    for (int o = 32; o > 0; o >>= 1) v += __shfl_xor(v, o, 64);
    return v;
}

// 16-lane-group reduce (xor offsets stay within the aligned 16-lane group)
__device__ __forceinline__ float gsum16(float v) {
    v += __shfl_xor(v, 1, 64);
    v += __shfl_xor(v, 2, 64);
    v += __shfl_xor(v, 4, 64);
    v += __shfl_xor(v, 8, 64);
    return v;
}

__device__ __forceinline__ float tanh_fast(float x) {
    const float e = __expf(2.0f * x);
    return (e - 1.0f) * __builtin_amdgcn_rcpf(e + 1.0f);
}

__device__ __forceinline__ float dot4(const float4 a, const float4 b) {
    return a.x * b.x + a.y * b.y + a.z * b.z + a.w * b.w;
}

// ---------------- fwd: one wave per (sample, side); float4-transposed gathers ----------------
// Lane l: slot-subgroup sub = l>>4 handles slot (4*it + sub); columns (l&15)*4..+3.
// All ds_bpermute index fetches hoisted into a branchless pre-pass (register arrays,
// constant indices) so the main loop is pure VMEM+VALU with no DS dependency.
__global__ __launch_bounds__(256, 4) void fwd_kernel(
    const int* __restrict__ user1, const int* __restrict__ item1,
    const int* __restrict__ user2, const int* __restrict__ item2,
    const int* __restrict__ u_his, const int* __restrict__ u_pos, const int* __restrict__ u_mask,
    const int* __restrict__ i_his, const int* __restrict__ i_pos, const int* __restrict__ i_mask,
    const float* __restrict__ user1_emb, const float* __restrict__ item1_emb,
    const float* __restrict__ user1_bias, const float* __restrict__ item1_bias,
    const float* __restrict__ u_pos_emb,
    const float* __restrict__ user2_emb, const float* __restrict__ item2_emb,
    const float* __restrict__ user2_bias, const float* __restrict__ item2_bias,
    const float* __restrict__ i_pos_emb,
    const float* __restrict__ attn_u_W, const float* __restrict__ attn_u_b,
    const float* __restrict__ attn_i_W, const float* __restrict__ attn_i_b,
    float* __restrict__ out, float* __restrict__ ws)
{
    const int wave = threadIdx.x >> 6;
    const int d = threadIdx.x & 63;
    const int b = __builtin_amdgcn_readfirstlane(blockIdx.x * 2 + (wave >> 1));
    const bool iw = (wave & 1);   // wave-uniform: false=U-side, true=I-side
    const int sub = d >> 4;       // slot subgroup 0..3
    const int col = (d & 15) * 4; // dword column of the row

    // zero the two loss accumulators (stream-ordered before reduce2's atomics)
    if (blockIdx.x == 0 && threadIdx.x == 0) {
        out[4 * NB] = 0.0f;
        out[4 * NB + 1] = 0.0f;
    }

    const int iu1 = user1[b], ii1 = item1[b], iu2 = user2[b], ii2 = item2[b];

    const int*   his  = iw ? i_his  : u_his;
    const int*   posa = iw ? i_pos  : u_pos;
    const int*   msk  = iw ? i_mask : u_mask;
    const float* ktab = iw ? user2_emb : item1_emb;
    const float* ptab = iw ? i_pos_emb : u_pos_emb;
    const float* W    = iw ? attn_i_W  : attn_u_W;
    const float  bb   = iw ? attn_i_b[0] : attn_u_b[0];

    // ---- slot metadata (lane = slot) ----
    int hidx = 0, hpos = 0;
    bool act = false;
    if (d < NH) {
        hidx = his[b * NH + d];
        hpos = posa[b * NH + d];
        act  = (msk[b * NH + d] != 0);
    }

    // ---- q rows + epilogue rows + weights in float4 layout ----
    const float* qa_tab = iw ? user2_emb : item1_emb;
    const float* qb_tab = iw ? user1_emb : item2_emb;
    const int    qidx   = iw ? iu1 : ii1;
    const float4 qa4 = *(const float4*)(qa_tab + (size_t)qidx * ND + col);
    const float4 qb4 = *(const float4*)(qb_tab + (size_t)qidx * ND + col);
    const float4 pa4 = *(const float4*)((iw ? item2_emb : user1_emb) +
                                        (size_t)(iw ? ii1 : iu1) * ND + col);
    const float4 ab4 = *(const float4*)((iw ? item2_emb : item1_emb) + (size_t)ii2 * ND + col);
    const float4 mb4 = *(const float4*)((iw ? user2_emb : user1_emb) + (size_t)iu2 * ND + col);
    const float4 Wq4 = *(const float4*)(W + col);
    const float4 Wk4 = *(const float4*)(W + ND + col);

    const float cq_a = wsum(dot4(qa4, Wq4)) * 0.25f + bb;
    const float cq_b = wsum(dot4(qb4, Wq4)) * 0.25f + bb;
    const float e0_a = __expf(tanh_fast(cq_a));
    const float e0_b = __expf(tanh_fast(cq_b));

    // ---- ballot compaction of active slots into lanes 0..nact-1 ----
    const unsigned long long bal = __ballot(act);
    const int nact = __builtin_amdgcn_readfirstlane(__popcll(bal));
    const int below = __builtin_amdgcn_mbcnt_hi(
        (unsigned)(bal >> 32), __builtin_amdgcn_mbcnt_lo((unsigned)bal, 0));
    const int tgt = (act ? below : 63) << 2;
    const int idx_c = __builtin_amdgcn_ds_permute(tgt, hidx);
    const int pos_c = __builtin_amdgcn_ds_permute(tgt, hpos);

    // ---- branchless pre-pass: hoist ALL bpermutes into register arrays ----
    int ihs[MAXIT], ips[MAXIT];
#pragma unroll
    for (int it = 0; it < MAXIT; ++it) {
        const int sid = it * 4 + sub;
        const int off = (sid < nact ? sid : 0) << 2;
        ihs[it] = __builtin_amdgcn_ds_bpermute(off, idx_c);
        ips[it] = __builtin_amdgcn_ds_bpermute(off, pos_c);
    }

    // ---- main loop: pure VMEM + VALU, no DS dependencies between iterations ----
    float4 oa = make_float4(0.f, 0.f, 0.f, 0.f);
    float4 ob = make_float4(0.f, 0.f, 0.f, 0.f);
    float den_a_acc = 0.0f, den_b_acc = 0.0f, reg = 0.0f;
    const int nit = (nact + 3) >> 2;
#pragma unroll
    for (int it = 0; it < MAXIT; ++it) {
        if (it < nit) {
            const bool v = (it * 4 + sub) < nact;
            const float4 kv = *(const float4*)(ktab + (size_t)ihs[it] * ND + col);
            const float4 pv = *(const float4*)(ptab + ips[it] * ND + col);
            float4 k;
            k.x = kv.x + pv.x; k.y = kv.y + pv.y; k.z = kv.z + pv.z; k.w = kv.w + pv.w;
            const float s = gsum16(dot4(k, Wk4));            // full-row key score
            float ea = __expf(tanh_fast(cq_a + s));
            float eb = __expf(tanh_fast(cq_b + s));
            ea = v ? ea : 0.0f;
            eb = v ? eb : 0.0f;
            oa.x += ea * k.x; oa.y += ea * k.y; oa.z += ea * k.z; oa.w += ea * k.w;
            ob.x += eb * k.x; ob.y += eb * k.y; ob.z += eb * k.z; ob.w += eb * k.w;
            den_a_acc += ea;
            den_b_acc += eb;
            reg += v ? dot4(kv, kv) : 0.0f;
        }
    }

    // each active slot's e counted 16x in den_acc
    const float den_a = wsum(den_a_acc) * 0.0625f + (float)(NH - nact) * e0_a;
    const float den_b = wsum(den_b_acc) * 0.0625f + (float)(NH - nact) * e0_b;

    // ---- epilogue: slots partitioned across lanes -> plain wsum is exact ----
    const float rd_a = __builtin_amdgcn_rcpf(den_a);
    const float rd_b = __builtin_amdgcn_rcpf(den_b);
    const float4 aa4 = iw ? pa4 : qa4;   // add_a
    const float4 ma4 = iw ? qa4 : pa4;   // mul_a
    const float l_a = wsum(dot4(oa, ma4) * rd_a + 0.25f * dot4(aa4, ma4));
    const float l_b = wsum(dot4(ob, mb4) * rd_b + 0.25f * dot4(ab4, mb4));
    const float rv = iw ? (dot4(mb4, mb4) + dot4(ab4, ab4))
                        : (dot4(ma4, ma4) + dot4(qa4, qa4));
    const float r = wsum(reg + 0.25f * rv);

    const float* ub = iw ? user2_bias : user1_bias;
    const float* ib = iw ? item2_bias : item1_bias;
    if (d == 0) {
        out[(iw ? NB : 0) + b]          = ub[iu1] + ib[ii1] + l_a;
        out[(iw ? 3 * NB : 2 * NB) + b] = ub[iu2] + ib[ii2] + l_b;
        ws[(iw ? NB : 0) + b] = r;
    }
}

// ---------------- 32-block reduce of ws partials into the two loss accums ----------------
__global__ __launch_bounds__(256, 8) void reduce2_kernel(
    const float* __restrict__ ws, float* __restrict__ out)
{
    const int i = blockIdx.x * 256 + threadIdx.x;   // grid 32 x 256 = 8192 = NB
    const float a = wsum(ws[i]);
    const float c = wsum(ws[NB + i]);
    __shared__ float sa[4], sc[4];
    const int w = threadIdx.x >> 6, d = threadIdx.x & 63;
    if (d == 0) { sa[w] = a; sc[w] = c; }
    __syncthreads();
    if (threadIdx.x == 0)  atomicAdd(&out[4 * NB],     sa[0] + sa[1] + sa[2] + sa[3]);
    if (threadIdx.x == 64) atomicAdd(&out[4 * NB + 1], sc[0] + sc[1] + sc[2] + sc[3]);
}

extern "C" void kernel_launch(void* const* d_in, const int* in_sizes, int n_in,
                              void* d_out, int out_size, void* d_ws, size_t ws_size,
                              hipStream_t stream) {
    const int* user1 = (const int*)d_in[0];
    const int* item1 = (const int*)d_in[1];
    const int* user2 = (const int*)d_in[2];
    const int* item2 = (const int*)d_in[3];
    const int* u_his = (const int*)d_in[4];
    const int* u_pos = (const int*)d_in[5];
    const int* u_msk = (const int*)d_in[6];
    const int* i_his = (const int*)d_in[7];
    const int* i_pos = (const int*)d_in[8];
    const int* i_msk = (const int*)d_in[9];
    const float* user1_emb  = (const float*)d_in[10];
    const float* item1_emb  = (const float*)d_in[11];
    const float* user1_bias = (const float*)d_in[12];
    const float* item1_bias = (const float*)d_in[13];
    const float* u_pos_emb  = (const float*)d_in[14];
    const float* user2_emb  = (const float*)d_in[15];
    const float* item2_emb  = (const float*)d_in[16];
    const float* user2_bias = (const float*)d_in[17];
    const float* item2_bias = (const float*)d_in[18];
    const float* i_pos_emb  = (const float*)d_in[19];
    const float* attn_u_W = (const float*)d_in[20];
    const float* attn_u_b = (const float*)d_in[21];
    const float* attn_i_W = (const float*)d_in[22];
    const float* attn_i_b = (const float*)d_in[23];
    float* out = (float*)d_out;
    float* ws  = (float*)d_ws;

    fwd_kernel<<<NB / 2, 256, 0, stream>>>(
        user1, item1, user2, item2,
        u_his, u_pos, u_msk, i_his, i_pos, i_msk,
        user1_emb, item1_emb, user1_bias, item1_bias, u_pos_emb,
        user2_emb, item2_emb, user2_bias, item2_bias, i_pos_emb,
        attn_u_W, attn_u_b, attn_i_W, attn_i_b,
        out, ws);
    reduce2_kernel<<<32, 256, 0, stream>>>(ws, out);
}

// Round 13
// 184.427 us; speedup vs baseline: 1.0223x; 1.0223x over previous
//
#include <hip/hip_runtime.h>

#define NB 8192
#define NH 50
#define ND 64

__device__ __forceinline__ float wsum(float v) {
#pragma unroll
    for (int o = 32; o > 0; o >>= 1) v += __shfl_xor(v, o, 64);
    return v;
}

// 16-lane-group reduce (groups = aligned 16-lane blocks; xor offsets stay in-group)
__device__ __forceinline__ float gsum16(float v) {
    v += __shfl_xor(v, 1, 64);
    v += __shfl_xor(v, 2, 64);
    v += __shfl_xor(v, 4, 64);
    v += __shfl_xor(v, 8, 64);
    return v;
}

__device__ __forceinline__ float tanh_fast(float x) {
    const float e = __expf(2.0f * x);
    return (e - 1.0f) * __builtin_amdgcn_rcpf(e + 1.0f);
}

__device__ __forceinline__ float dot4(const float4 a, const float4 b) {
    return a.x * b.x + a.y * b.y + a.z * b.z + a.w * b.w;
}

// ---------------- fwd: one wave per (sample, side); float4-transposed gathers ----------------
// Lane l: slot-subgroup sub = l>>4, row dword-columns (l&15)*4..+3. One wave64 dwordx4
// load = 4 full rows. Scores computed IN-LOOP via 16-lane butterfly of dot4(k, Wk4).
// Slots partitioned across lanes => plain wsum of per-lane partial dots is exact;
// wave-uniform terms carry x0.25; den counted 16x => x(1/16).
// launch_bounds(256,8): R12 showed occupancy was capped at 50% by (256,4); the gather
// latency needs the full 32 waves/CU.
__global__ __launch_bounds__(256, 8) void fwd_kernel(
    const int* __restrict__ user1, const int* __restrict__ item1,
    const int* __restrict__ user2, const int* __restrict__ item2,
    const int* __restrict__ u_his, const int* __restrict__ u_pos, const int* __restrict__ u_mask,
    const int* __restrict__ i_his, const int* __restrict__ i_pos, const int* __restrict__ i_mask,
    const float* __restrict__ user1_emb, const float* __restrict__ item1_emb,
    const float* __restrict__ user1_bias, const float* __restrict__ item1_bias,
    const float* __restrict__ u_pos_emb,
    const float* __restrict__ user2_emb, const float* __restrict__ item2_emb,
    const float* __restrict__ user2_bias, const float* __restrict__ item2_bias,
    const float* __restrict__ i_pos_emb,
    const float* __restrict__ attn_u_W, const float* __restrict__ attn_u_b,
    const float* __restrict__ attn_i_W, const float* __restrict__ attn_i_b,
    float* __restrict__ out, float* __restrict__ ws)
{
    const int wave = threadIdx.x >> 6;
    const int d = threadIdx.x & 63;
    const int b = __builtin_amdgcn_readfirstlane(blockIdx.x * 2 + (wave >> 1));
    const bool iw = (wave & 1);   // wave-uniform: false=U-side, true=I-side
    const int sub = d >> 4;       // slot subgroup 0..3
    const int col = (d & 15) * 4; // dword column of the row

    // zero the two loss accumulators (stream-ordered before reduce2's atomics)
    if (blockIdx.x == 0 && threadIdx.x == 0) {
        out[4 * NB] = 0.0f;
        out[4 * NB + 1] = 0.0f;
    }

    const int iu1 = user1[b], ii1 = item1[b], iu2 = user2[b], ii2 = item2[b];

    const int*   his  = iw ? i_his  : u_his;
    const int*   posa = iw ? i_pos  : u_pos;
    const int*   msk  = iw ? i_mask : u_mask;
    const float* ktab = iw ? user2_emb : item1_emb;
    const float* ptab = iw ? i_pos_emb : u_pos_emb;
    const float* W    = iw ? attn_i_W  : attn_u_W;
    const float  bb   = iw ? attn_i_b[0] : attn_u_b[0];

    // ---- slot metadata (lane = slot) ----
    int hidx = 0, hpos = 0;
    bool act = false;
    if (d < NH) {
        hidx = his[b * NH + d];
        hpos = posa[b * NH + d];
        act  = (msk[b * NH + d] != 0);
    }

    // ---- q rows + epilogue rows + weights in float4 layout ----
    const float* qa_tab = iw ? user2_emb : item1_emb;
    const float* qb_tab = iw ? user1_emb : item2_emb;
    const int    qidx   = iw ? iu1 : ii1;
    const float4 qa4 = *(const float4*)(qa_tab + (size_t)qidx * ND + col);
    const float4 qb4 = *(const float4*)(qb_tab + (size_t)qidx * ND + col);
    const float4 pa4 = *(const float4*)((iw ? item2_emb : user1_emb) +
                                        (size_t)(iw ? ii1 : iu1) * ND + col);
    const float4 ab4 = *(const float4*)((iw ? item2_emb : item1_emb) + (size_t)ii2 * ND + col);
    const float4 mb4 = *(const float4*)((iw ? user2_emb : user1_emb) + (size_t)iu2 * ND + col);
    const float4 Wq4 = *(const float4*)(W + col);
    const float4 Wk4 = *(const float4*)(W + ND + col);

    const float cq_a = wsum(dot4(qa4, Wq4)) * 0.25f + bb;
    const float cq_b = wsum(dot4(qb4, Wq4)) * 0.25f + bb;
    const float e0_a = __expf(tanh_fast(cq_a));
    const float e0_b = __expf(tanh_fast(cq_b));

    // ---- ballot compaction of active slots into lanes 0..nact-1 ----
    const unsigned long long bal = __ballot(act);
    const int nact = __builtin_amdgcn_readfirstlane(__popcll(bal));
    const int below = __builtin_amdgcn_mbcnt_hi(
        (unsigned)(bal >> 32), __builtin_amdgcn_mbcnt_lo((unsigned)bal, 0));
    const int tgt = (act ? below : 63) << 2;
    const int idx_c = __builtin_amdgcn_ds_permute(tgt, hidx);
    const int pos_c = __builtin_amdgcn_ds_permute(tgt, hpos);

    // ---- transposed gather loop: 4 slots/iter, 2 VMEM insts, in-loop score ----
    float4 oa = make_float4(0.f, 0.f, 0.f, 0.f);
    float4 ob = make_float4(0.f, 0.f, 0.f, 0.f);
    float den_a_acc = 0.0f, den_b_acc = 0.0f, reg = 0.0f;
#pragma unroll 4
    for (int base = 0; base < nact; base += 4) {
        const int sid = base + sub;
        const bool v = sid < nact;
        const int off = (v ? sid : 0) << 2;
        const int ih = __builtin_amdgcn_ds_bpermute(off, idx_c);
        const int ip = __builtin_amdgcn_ds_bpermute(off, pos_c);
        const float4 kv = *(const float4*)(ktab + (size_t)ih * ND + col);
        const float4 pv = *(const float4*)(ptab + ip * ND + col);
        float4 k;
        k.x = kv.x + pv.x; k.y = kv.y + pv.y; k.z = kv.z + pv.z; k.w = kv.w + pv.w;
        const float s = gsum16(dot4(k, Wk4));            // full-row key score
        float ea = __expf(tanh_fast(cq_a + s));
        float eb = __expf(tanh_fast(cq_b + s));
        ea = v ? ea : 0.0f;
        eb = v ? eb : 0.0f;
        oa.x += ea * k.x; oa.y += ea * k.y; oa.z += ea * k.z; oa.w += ea * k.w;
        ob.x += eb * k.x; ob.y += eb * k.y; ob.z += eb * k.z; ob.w += eb * k.w;
        den_a_acc += ea;
        den_b_acc += eb;
        reg += v ? dot4(kv, kv) : 0.0f;
    }

    // each active slot's e counted 16x in den_acc
    const float den_a = wsum(den_a_acc) * 0.0625f + (float)(NH - nact) * e0_a;
    const float den_b = wsum(den_b_acc) * 0.0625f + (float)(NH - nact) * e0_b;

    // ---- epilogue: slots partitioned across lanes -> plain wsum is exact ----
    const float rd_a = __builtin_amdgcn_rcpf(den_a);
    const float rd_b = __builtin_amdgcn_rcpf(den_b);
    const float4 aa4 = iw ? pa4 : qa4;   // add_a
    const float4 ma4 = iw ? qa4 : pa4;   // mul_a
    const float l_a = wsum(dot4(oa, ma4) * rd_a + 0.25f * dot4(aa4, ma4));
    const float l_b = wsum(dot4(ob, mb4) * rd_b + 0.25f * dot4(ab4, mb4));
    const float rv = iw ? (dot4(mb4, mb4) + dot4(ab4, ab4))
                        : (dot4(ma4, ma4) + dot4(qa4, qa4));
    const float r = wsum(reg + 0.25f * rv);

    const float* ub = iw ? user2_bias : user1_bias;
    const float* ib = iw ? item2_bias : item1_bias;
    if (d == 0) {
        out[(iw ? NB : 0) + b]          = ub[iu1] + ib[ii1] + l_a;
        out[(iw ? 3 * NB : 2 * NB) + b] = ub[iu2] + ib[ii2] + l_b;
        ws[(iw ? NB : 0) + b] = r;
    }
}

// ---------------- 32-block reduce of ws partials into the two loss accums ----------------
__global__ __launch_bounds__(256, 8) void reduce2_kernel(
    const float* __restrict__ ws, float* __restrict__ out)
{
    const int i = blockIdx.x * 256 + threadIdx.x;   // grid 32 x 256 = 8192 = NB
    const float a = wsum(ws[i]);
    const float c = wsum(ws[NB + i]);
    __shared__ float sa[4], sc[4];
    const int w = threadIdx.x >> 6, d = threadIdx.x & 63;
    if (d == 0) { sa[w] = a; sc[w] = c; }
    __syncthreads();
    if (threadIdx.x == 0)  atomicAdd(&out[4 * NB],     sa[0] + sa[1] + sa[2] + sa[3]);
    if (threadIdx.x == 64) atomicAdd(&out[4 * NB + 1], sc[0] + sc[1] + sc[2] + sc[3]);
}

extern "C" void kernel_launch(void* const* d_in, const int* in_sizes, int n_in,
                              void* d_out, int out_size, void* d_ws, size_t ws_size,
                              hipStream_t stream) {
    const int* user1 = (const int*)d_in[0];
    const int* item1 = (const int*)d_in[1];
    const int* user2 = (const int*)d_in[2];
    const int* item2 = (const int*)d_in[3];
    const int* u_his = (const int*)d_in[4];
    const int* u_pos = (const int*)d_in[5];
    const int* u_msk = (const int*)d_in[6];
    const int* i_his = (const int*)d_in[7];
    const int* i_pos = (const int*)d_in[8];
    const int* i_msk = (const int*)d_in[9];
    const float* user1_emb  = (const float*)d_in[10];
    const float* item1_emb  = (const float*)d_in[11];
    const float* user1_bias = (const float*)d_in[12];
    const float* item1_bias = (const float*)d_in[13];
    const float* u_pos_emb  = (const float*)d_in[14];
    const float* user2_emb  = (const float*)d_in[15];
    const float* item2_emb  = (const float*)d_in[16];
    const float* user2_bias = (const float*)d_in[17];
    const float* item2_bias = (const float*)d_in[18];
    const float* i_pos_emb  = (const float*)d_in[19];
    const float* attn_u_W = (const float*)d_in[20];
    const float* attn_u_b = (const float*)d_in[21];
    const float* attn_i_W = (const float*)d_in[22];
    const float* attn_i_b = (const float*)d_in[23];
    float* out = (float*)d_out;
    float* ws  = (float*)d_ws;

    fwd_kernel<<<NB / 2, 256, 0, stream>>>(
        user1, item1, user2, item2,
        u_his, u_pos, u_msk, i_his, i_pos, i_msk,
        user1_emb, item1_emb, user1_bias, item1_bias, u_pos_emb,
        user2_emb, item2_emb, user2_bias, item2_bias, i_pos_emb,
        attn_u_W, attn_u_b, attn_i_W, attn_i_b,
        out, ws);
    reduce2_kernel<<<32, 256, 0, stream>>>(ws, out);
}